// Round 12
// baseline (15945.703 us; speedup 1.0000x reference)
//
#include <hip/hip_runtime.h>

#define TT 800
#define BB 128
#define HH 256
#define UU 64
#define AA 64
#define KK 10
#define GG 20
#define NWG 256
#define GB 32          // batches per group
#define NGRP 4

typedef float f32x4 __attribute__((ext_vector_type(4)));
typedef __bf16 bf16y8 __attribute__((ext_vector_type(8)));
typedef short bf16s8 __attribute__((ext_vector_type(8)));

__device__ __forceinline__ float bf2f(unsigned short u) {
  return __uint_as_float(((unsigned int)u) << 16);
}
__device__ __forceinline__ unsigned short f2bf(float f) {
  unsigned int x = __float_as_uint(f);
  x += 0x7FFFu + ((x >> 16) & 1u);
  return (unsigned short)(x >> 16);
}
__device__ __forceinline__ unsigned packf(float v) {
  unsigned short hi = f2bf(v);
  unsigned short lo = f2bf(v - bf2f(hi));
  return (unsigned)hi | ((unsigned)lo << 16);
}
__device__ __forceinline__ float unpackf(unsigned u) {
  return bf2f((unsigned short)(u & 0xFFFF)) + bf2f((unsigned short)(u >> 16));
}
__device__ __forceinline__ float sigm(float x) { return 1.0f / (1.0f + __expf(-x)); }
__device__ __forceinline__ float rin(const void* p, size_t i, bool f32) {
  return f32 ? ((const float*)p)[i] : bf2f(((const unsigned short*)p)[i]);
}
__device__ __forceinline__ bf16y8 ld8(const unsigned short* p) {
  return __builtin_bit_cast(bf16y8, *(const bf16s8*)p);
}

// agent-scope relaxed atomics: sc1 accesses at the L3 coherence point
__device__ __forceinline__ unsigned ald(const unsigned* p) {
  return __hip_atomic_load(p, __ATOMIC_RELAXED, __HIP_MEMORY_SCOPE_AGENT);
}
__device__ __forceinline__ void ast(unsigned* p, unsigned v) {
  __hip_atomic_store(p, v, __ATOMIC_RELAXED, __HIP_MEMORY_SCOPE_AGENT);
}
__device__ __forceinline__ unsigned aadd(unsigned* p) {
  return __hip_atomic_fetch_add(p, 1u, __ATOMIC_RELAXED, __HIP_MEMORY_SCOPE_AGENT);
}

// State planes are k-major: plane[kblk][b][j], kblk=hu>>3, j=hu&7.
// Flat: kblk*1024 + b*8 + j  (1024 = BB*8). Coalesced 32B/lane gate reads.

struct KArgs {
  const void* in[27];
  float* out;
  float* kappa;
  unsigned *xu;               // packed x, [t][b][3], 307200
  unsigned *wu;               // packed w, k-major, 8192
  unsigned *h1[2], *h2[2], *h3[2];  // packed h planes, k-major, 32768 each
  unsigned* bar;
  // bar lines (32 uints each): [0]=full cnt; [1..4]=group roots; [8..39]=subs
  // (grp*8+s); [64..319]=per-WG flags
};

// LDS B-fragment fill, hi/lo planes
__device__ void fillB(unsigned short* Bhi, unsigned short* Blo, const void* Wih,
                      const void* Whh, int KP, int ihCols, int ihEnd, int hhStart,
                      int q, int tid, bool f32) {
  int total = KP * 16;
  for (int idx = tid; idx < total; idx += 256) {
    int k = idx >> 4, n = idx & 15;
    int row = (n >> 2) * HH + q * 4 + (n & 3);
    float v = 0.f;
    if (k < 3) v = rin(Wih, (size_t)row * ihCols + k, f32);
    else if (k >= 8 && k < ihEnd) v = rin(Wih, (size_t)row * ihCols + (k - 5), f32);
    else if (k >= hhStart && k < hhStart + 256) v = rin(Whh, (size_t)row * HH + (k - hhStart), f32);
    unsigned short hi = f2bf(v);
    int a = ((k >> 3) * 16 + n) * 8 + (k & 7);
    Bhi[a] = hi;
    Blo[a] = f2bf(v - bf2f(hi));
  }
}

// MFMA hi/lo gate stage on wave pair `wsel` (0 -> waves 0-1, 1 -> waves 2-3).
// A regions: kc0/quad0 -> x(3), [8,72) -> w, [72,328) -> r2, [328,584) -> r3.
template <int KC, bool R3>
__device__ __forceinline__ void gate_mfma(
    const unsigned* __restrict__ xt, const unsigned* __restrict__ wu,
    const unsigned* __restrict__ r2, const unsigned* __restrict__ r3,
    const unsigned short* __restrict__ Bhi, const unsigned short* __restrict__ Blo,
    const float* __restrict__ bias4, float& creg, unsigned* __restrict__ hout,
    int grp, int q, float* zls, int tid, int wsel) {
  const int wavep = tid >> 6;
  const int wv = wavep - 2 * wsel;
  if ((unsigned)wv >= 2u) return;
  const int lane = tid & 63;
  const int n15 = lane & 15, quad = lane >> 4;
  const int b = grp * GB + wv * 16 + n15;

  unsigned xv0 = 0, xv1 = 0, xv2 = 0;
  if (quad == 0) {
    xv0 = ald(xt + b * 3 + 0);
    xv1 = ald(xt + b * 3 + 1);
    xv2 = ald(xt + b * 3 + 2);
  }

  constexpr int DEP = 8;
  unsigned long long buf[DEP][4];

  // k-major planes: block of 8 packed elems for (kblk, b) at plane + kblk*1024 + b*8
  auto issue = [&](int kc) {
    const int k0 = kc * 32 + quad * 8;
    const unsigned* p;
    if (kc == 0 && quad == 0) p = nullptr;
    else if (k0 < 72) p = wu + ((k0 - 8) >> 3) * 1024 + b * 8;
    else if (k0 < 328) p = r2 + ((k0 - 72) >> 3) * 1024 + b * 8;
    else if (R3 && k0 < 584) p = r3 + ((k0 - 328) >> 3) * 1024 + b * 8;
    else p = nullptr;
    unsigned long long* d = buf[kc & (DEP - 1)];
    if (p) {
      const unsigned long long* q8 = (const unsigned long long*)p;
#pragma unroll
      for (int j = 0; j < 4; ++j)
        d[j] = __hip_atomic_load(q8 + j, __ATOMIC_RELAXED, __HIP_MEMORY_SCOPE_AGENT);
    } else {
#pragma unroll
      for (int j = 0; j < 4; ++j) d[j] = 0ull;
    }
  };

#pragma unroll
  for (int kc = 0; kc < DEP && kc < KC; ++kc) issue(kc);

  f32x4 acc = {0.f, 0.f, 0.f, 0.f};
#pragma unroll
  for (int kc = 0; kc < KC; ++kc) {
    unsigned long long* s = buf[kc & (DEP - 1)];
    bf16s8 th, tl;
#pragma unroll
    for (int j = 0; j < 4; ++j) {
      unsigned lo32 = (unsigned)s[j], hi32 = (unsigned)(s[j] >> 32);
      th[2 * j] = (short)(lo32 & 0xFFFFu);     tl[2 * j] = (short)(lo32 >> 16);
      th[2 * j + 1] = (short)(hi32 & 0xFFFFu); tl[2 * j + 1] = (short)(hi32 >> 16);
    }
    if (kc == 0 && quad == 0) {
      th[0] = (short)(xv0 & 0xFFFFu); tl[0] = (short)(xv0 >> 16);
      th[1] = (short)(xv1 & 0xFFFFu); tl[1] = (short)(xv1 >> 16);
      th[2] = (short)(xv2 & 0xFFFFu); tl[2] = (short)(xv2 >> 16);
    }
    bf16y8 ah = __builtin_bit_cast(bf16y8, th);
    bf16y8 al = __builtin_bit_cast(bf16y8, tl);
    const int boff = ((kc * 4 + quad) * 16 + n15) * 8;
    bf16y8 bh = ld8(Bhi + boff), bl = ld8(Blo + boff);
    acc = __builtin_amdgcn_mfma_f32_16x16x32_bf16(ah, bh, acc, 0, 0, 0);
    acc = __builtin_amdgcn_mfma_f32_16x16x32_bf16(ah, bl, acc, 0, 0, 0);
    acc = __builtin_amdgcn_mfma_f32_16x16x32_bf16(al, bh, acc, 0, 0, 0);
    if (kc + DEP < KC) issue(kc + DEP);
  }

  // wave-private LDS transpose (physical-wave slice)
  float* zw = zls + wavep * (16 * 17);
#pragma unroll
  for (int r = 0; r < 4; ++r) zw[(quad * 4 + r) * 17 + n15] = acc[r];
  const int m = lane >> 2, j = lane & 3;
  const int hu = q * 4 + j;
  const int bb = grp * GB + wv * 16 + m;
  float zi = zw[m * 17 + (0 + j)]  + bias4[0];
  float zf = zw[m * 17 + (4 + j)]  + bias4[1];
  float zg = zw[m * 17 + (8 + j)]  + bias4[2];
  float zo = zw[m * 17 + (12 + j)] + bias4[3];
  float cn = sigm(zf) * creg + sigm(zi) * tanhf(zg);
  creg = cn;
  float hn = sigm(zo) * tanhf(cn);
  ast(hout + (hu >> 3) * 1024 + bb * 8 + (hu & 7), packf(hn));
}

// Attention window for batch b (whole WG).
template <bool F32>
__device__ void window_stage(const KArgs& a, int b, const unsigned* __restrict__ h1c,
                             int tid, float* misc) {
  float* shm  = misc;        // 256
  float* part = misc + 256;  // 240
  float* win  = misc + 500;  // 30
  float* kap  = misc + 530;  // 10
  float* phi  = misc + 544;  // 64
  shm[tid] = unpackf(ald(h1c + (tid >> 3) * 1024 + b * 8 + (tid & 7)));
  __syncthreads();
  if (tid < 240) {
    int r = tid >> 3, pp = tid & 7;
    float s = 0.f;
#pragma unroll 8
    for (int i = 0; i < 32; ++i) s += rin(a.in[11], r * HH + pp * 32 + i, F32) * shm[pp * 32 + i];
    part[tid] = s;
  }
  __syncthreads();
  if (tid < 30) {
    float s = rin(a.in[12], tid, F32);
#pragma unroll
    for (int i = 0; i < 8; ++i) s += part[tid * 8 + i];
    win[tid] = __expf(s);
  }
  __syncthreads();
  if (tid < 10) {
    float kp = a.kappa[b * KK + tid] + 0.1f * win[20 + tid];
    a.kappa[b * KK + tid] = kp;
    kap[tid] = kp;
  }
  __syncthreads();
  if (tid < 64) {
    float u = (float)tid, s = 0.f;
#pragma unroll
    for (int r = 0; r < 10; ++r) {
      float d = kap[r] - u;
      s += win[r] * __expf(-win[10 + r] * d * d);
    }
    phi[tid] = s;
  }
  __syncthreads();
  if (tid < 64) {
    float s = 0.f;
    for (int u = 0; u < 64; ++u) s += phi[u] * rin(a.in[1], ((size_t)b * UU + u) * AA + tid, F32);
    ast(a.wu + (tid >> 3) * 1024 + b * 8 + (tid & 7), packf(s));
  }
}

// Output projections for timestep tt, batch b (whole WG).
template <bool F32>
__device__ void proj_stage(const KArgs& a, int tt, const unsigned* __restrict__ h3b,
                           int b, int tid, float* misc) {
  float* shm  = misc;        // 256
  float* part = misc + 256;  // 242
  float* zp   = misc + 500;  // 121
  shm[tid] = unpackf(ald(h3b + (tid >> 3) * 1024 + b * 8 + (tid & 7)));
  __syncthreads();
  if (tid < 242) {
    int o = tid >> 1, hf = tid & 1;
    const void* Wt;
    const void* bt;
    int rr;
    if (o == 0) {
      Wt = a.in[13]; bt = a.in[14]; rr = 0;
    } else {
      int fam = (o - 1) / 20;
      rr = (o - 1) % 20;
      Wt = a.in[15 + fam * 2];
      bt = a.in[16 + fam * 2];
    }
    float s0 = hf ? 0.f : rin(bt, rr, F32), s1 = 0.f;
    const float* hh = shm + hf * 128;
#pragma unroll 8
    for (int i = 0; i < 128; i += 2) {
      s0 += rin(Wt, (size_t)rr * HH + hf * 128 + i, F32) * hh[i];
      s1 += rin(Wt, (size_t)rr * HH + hf * 128 + i + 1, F32) * hh[i + 1];
    }
    part[tid] = s0 + s1;
  }
  __syncthreads();
  if (tid < 121) zp[tid] = part[tid * 2] + part[tid * 2 + 1];
  __syncthreads();
  size_t tb = (size_t)tt * BB + b;
  if (tid == 0) {
    a.out[tb] = 1.f / (1.f + __expf(zp[0]));  // sigmoid(-z)
  } else if (tid < 121) {
    int fam = (tid - 1) / 20, g = (tid - 1) % 20;
    float z = zp[tid];
    float val;
    if (fam == 0) {
      float mx = -1e30f;
      for (int jj = 0; jj < 20; ++jj) mx = fmaxf(mx, zp[1 + jj]);
      float den = 0.f;
      for (int jj = 0; jj < 20; ++jj) den += __expf(zp[1 + jj] - mx);
      val = __expf(z - mx) / den;
    } else if (fam <= 2) {
      val = z;
    } else if (fam <= 4) {
      val = __expf(z);
    } else {
      val = tanhf(z);
    }
    a.out[(size_t)102400 + (size_t)fam * 2048000 + tb * GG + g] = val;
  }
}

#define BAR_WORDS (320 * 32)

__global__ void __launch_bounds__(256) bar_init_kernel(unsigned* bar) {
  for (int i = threadIdx.x; i < BAR_WORDS; i += 256) bar[i] = 0u;
}

__global__ void __launch_bounds__(256, 1) hsm_kernel(KArgs a) {
  __shared__ unsigned short B1h[5632], B1l[5632];
  __shared__ unsigned short B2h[9728], B2l[9728];
  __shared__ unsigned short B3h[9728], B3l[9728];
  __shared__ float zls[4 * 16 * 17];
  __shared__ float misc[768];
  __shared__ unsigned islast;

  const int tid = threadIdx.x;
  const int wg = blockIdx.x;
  const int grp = wg >> 6;   // batch group of 32
  const int q = wg & 63;     // hidden quad
  unsigned* cnt_full = a.bar;                                // line 0
  unsigned* root     = a.bar + (1 + grp) * 32;               // lines 1..4
  unsigned* sub      = a.bar + (8 + grp * 8 + (q & 7)) * 32; // lines 8..39
  unsigned* flags    = a.bar + 64 * 32;                      // lines 64..319
  unsigned* myflag   = flags + wg * 32;
  unsigned* gflag    = flags + (grp * 64) * 32;

  // Tree barrier: 8-way sub arrivals -> root -> flat flag broadcast.
  auto gb_grp = [&](unsigned ph) {   // phase >= 1; flag value = ph+1
    __syncthreads();
    if (tid == 0) {
      unsigned so = aadd(sub);
      if (so == ph * 8u - 1u) {
        unsigned ro = aadd(root);
        islast = (ro == ph * 8u - 1u) ? 1u : 0u;
      } else {
        islast = 0u;
      }
    }
    __syncthreads();
    if (islast) {
      if (tid < 64) ast(gflag + tid * 32, ph + 1u);
    } else if (tid == 0) {
      while (ald(myflag) < ph + 1u) __builtin_amdgcn_s_sleep(1);
    }
    __syncthreads();
  };
  auto gb_full = [&]() {             // once; flag value 1
    __syncthreads();
    if (tid == 0) {
      unsigned old = aadd(cnt_full);
      islast = (old == NWG - 1u) ? 1u : 0u;
    }
    __syncthreads();
    if (islast) {
      ast(flags + tid * 32, 1u);     // 256 threads cover 256 WGs
    } else if (tid == 0) {
      while (ald(myflag) < 1u) __builtin_amdgcn_s_sleep(1);
    }
    __syncthreads();
  };

  // ---- dtype sniff (uniform) ----
  bool isf32;
  {
    const unsigned short* w = (const unsigned short*)a.in[3];
    int cnt = 0;
    for (int i = 0; i < 128; ++i) {
      float v = bf2f(w[i]);
      if (!(fabsf(v) <= 100.f)) cnt++;
    }
    isf32 = (cnt > 0);
  }

  // ---- init (all cross-WG state through sc1 atomics) ----
  const int g0 = wg * 256 + tid, gs = 65536;
  if (isf32) {
    const float* xp = (const float*)a.in[0];
    for (int i = g0; i < 307200; i += gs) ast(a.xu + i, packf(xp[i]));
  } else {
    const unsigned short* xp = (const unsigned short*)a.in[0];
    for (int i = g0; i < 307200; i += gs) ast(a.xu + i, (unsigned)xp[i]);
  }
  if (g0 < 32768) {
    ast(a.h1[0] + g0, 0u); ast(a.h1[1] + g0, 0u);
    ast(a.h2[0] + g0, 0u); ast(a.h2[1] + g0, 0u);
    ast(a.h3[0] + g0, 0u); ast(a.h3[1] + g0, 0u);
  }
  if (g0 < 8192) ast(a.wu + g0, 0x00003F80u);   // w init = 1.0
  if (q < GB && tid < KK) a.kappa[(grp * GB + q) * KK + tid] = 0.f;

  float bs1[4], bs2[4], bs3[4];
  {
    const int hu = q * 4 + (tid & 3);
#pragma unroll
    for (int g = 0; g < 4; ++g) {
      bs1[g] = rin(a.in[4], g * HH + hu, isf32);
      bs2[g] = rin(a.in[7], g * HH + hu, isf32);
      bs3[g] = rin(a.in[10], g * HH + hu, isf32);
    }
  }
  float c1r = 0.f, c2r = 0.f, c3r = 0.f;   // c1r owned by waves 2-3; c2r/c3r by waves 0-1

  fillB(B1h, B1l, a.in[2], a.in[3], 352, 67, 72, 72, q, tid, isf32);
  fillB(B2h, B2l, a.in[5], a.in[6], 608, 323, 328, 328, q, tid, isf32);
  fillB(B3h, B3l, a.in[8], a.in[9], 608, 323, 328, 328, q, tid, isf32);
  gb_full();   // full grid once

  unsigned ph = 0;

  // prologue: LSTM1(t=0): rec h1[0]=0, w=ones -> h1[1]  (waves 2-3, own c1r)
  gate_mfma<11, false>(a.xu, a.wu, a.h1[0], nullptr, B1h, B1l, bs1, c1r,
                       a.h1[1], grp, q, zls, tid, 1);
  ++ph; gb_grp(ph);

  for (int t = 0; t < TT; ++t) {
    const int p = t & 1;
    const unsigned* xt = a.xu + (size_t)t * BB * 3;
    // Stage B: window(t) on WGs q<32, proj(t-1) on WGs q>=32 (parallel)
    if (q < GB) {
      if (isf32) window_stage<true>(a, grp * GB + q, a.h1[1 - p], tid, misc);
      else       window_stage<false>(a, grp * GB + q, a.h1[1 - p], tid, misc);
    } else if (t > 0) {
      if (isf32) proj_stage<true>(a, t - 1, a.h3[p], grp * GB + q - GB, tid, misc);
      else       proj_stage<false>(a, t - 1, a.h3[p], grp * GB + q - GB, tid, misc);
    }
    ++ph; gb_grp(ph);
    // Stage C: LSTM2(t) on waves 0-1
    gate_mfma<19, true>(xt, a.wu, a.h1[1 - p], a.h2[p], B2h, B2l,
                        bs2, c2r, a.h2[1 - p], grp, q, zls, tid, 0);
    ++ph; gb_grp(ph);
    // Stage D: LSTM3(t) on waves 0-1  ||  LSTM1(t+1) on waves 2-3
    gate_mfma<19, true>(xt, a.wu, a.h2[1 - p], a.h3[p], B3h, B3l,
                        bs3, c3r, a.h3[1 - p], grp, q, zls, tid, 0);
    if (t < TT - 1) {
      gate_mfma<11, false>(xt + BB * 3, a.wu, a.h1[1 - p], nullptr,
                           B1h, B1l, bs1, c1r, a.h1[p], grp, q, zls, tid, 1);
    }
    ++ph; gb_grp(ph);
  }
  if (q >= GB) {
    if (isf32) proj_stage<true>(a, TT - 1, a.h3[0], grp * GB + q - GB, tid, misc);
    else       proj_stage<false>(a, TT - 1, a.h3[0], grp * GB + q - GB, tid, misc);
  }
}

extern "C" void kernel_launch(void* const* d_in, const int* in_sizes, int n_in,
                              void* d_out, int out_size, void* d_ws, size_t ws_size,
                              hipStream_t stream) {
  KArgs a;
  for (int i = 0; i < 27; ++i) a.in[i] = d_in[i];
  a.out = (float*)d_out;

  char* ws = (char*)d_ws;
  size_t off = 0;
  auto take = [&](size_t bytes) {
    void* p = ws + off;
    off = (off + bytes + 127) & ~(size_t)127;
    return p;
  };
  a.kappa = (float*)take(1280 * 4);
  a.wu    = (unsigned*)take(8192 * 4);
  a.h1[0] = (unsigned*)take(32768 * 4);
  a.h1[1] = (unsigned*)take(32768 * 4);
  a.h2[0] = (unsigned*)take(32768 * 4);
  a.h2[1] = (unsigned*)take(32768 * 4);
  a.h3[0] = (unsigned*)take(32768 * 4);
  a.h3[1] = (unsigned*)take(32768 * 4);
  a.xu    = (unsigned*)take(307200 * 4);
  a.bar   = (unsigned*)take(BAR_WORDS * 4);

  bar_init_kernel<<<1, 256, 0, stream>>>(a.bar);
  hsm_kernel<<<NWG, 256, 0, stream>>>(a);
}